// Round 6
// baseline (427.029 us; speedup 1.0000x reference)
//
#include <hip/hip_runtime.h>
#include <hip/hip_bf16.h>

typedef __hip_bfloat16 bf16;
__device__ __forceinline__ float b2f(bf16 v){ return __bfloat162float(v); }

typedef __attribute__((ext_vector_type(8))) short s8v;
typedef __attribute__((ext_vector_type(4))) float f4v;

#define N_NODES 16384
#define N_EDGES 65536
#define NB 256
#define LSEQ 1000
#define BN_EPS 1e-5f
#define W1O 985
#define W2O 970
#define W3O 955

// ---- dtype flag: 1 if float inputs are f32, 0 if bf16 (measured: f32 on this harness) ----
__device__ int g_isf32;

__device__ __forceinline__ float LD(const void* p, int i, int f){
    return f ? ((const float*)p)[i] : b2f(((const bf16*)p)[i]);
}

// f32 -> bf16 bits, round-to-nearest-even
__device__ __forceinline__ unsigned short f2b(float x){
    unsigned u = __float_as_uint(x);
    return (unsigned short)((u + 0x7FFFu + ((u >> 16) & 1u)) >> 16);
}
__device__ __forceinline__ float bb2f(unsigned short h){
    return __uint_as_float(((unsigned)h) << 16);
}

// ---- intermediates in device globals ----
__device__ float g_hA[N_NODES*32];
__device__ float g_hB[N_NODES*32];
__device__ float g_xd[NB*128];
__device__ float g_P[16*26*32];
__device__ float g_wsum[32*128];
__device__ float g_xdb[NB*32];
__device__ float g_xcm[NB*32];
// pre-packed conv weights in per-lane B-FRAGMENT order (s8v granularity):
// s8v index = ktg*256 + ogrp*128 + hl*64 + lane
__device__ __attribute__((aligned(16))) unsigned short g_wf[2][32768];
// CSR of the (fixed) edge list, destination-major
// INVARIANT: g_deg is zero at k_prep entry (zero-init at load; k_scan re-zeroes
// it after consuming it each iteration) -> k_count can run inside k_prep.
__device__ int g_deg[N_NODES];
__device__ int g_cur[N_NODES];
__device__ int g_rowptr[N_NODES + 1];
__device__ int g_csrc[N_EDGES];
__device__ int g_gstart[NB + 1];     // per-graph node ranges (batch is sorted)

// ================= PREP KERNEL (GIN-chain prerequisites only) =============
#define PREP_BLOCKS 2305

__global__ __launch_bounds__(256) void k_prep(
    const void* x, const int* __restrict__ ei, const int* __restrict__ batch,
    const void* g1W1)
{
    __shared__ float sW1[78*32];
    __shared__ float sx[8][78];
    __shared__ int s_cnt;
    int tid = threadIdx.x, bid = blockIdx.x;

    // per-block dtype detect (same statistic as legacy k_dtype)
    if (tid == 0) s_cnt = 0;
    __syncthreads();
    {
        const unsigned short* u = (const unsigned short*)x;
        int bad = 0;
        for (int i = tid; i < 512; i += 256){
            unsigned short h = u[i];
            int ex = (h >> 7) & 0xFF;
            if (!(h == 0 || (ex >= 96 && ex <= 142))) bad++;
        }
        if (bad) atomicAdd(&s_cnt, bad);
    }
    __syncthreads();
    const int F = (s_cnt > 50) ? 1 : 0;
    if (bid == 0 && tid == 0) g_isf32 = F;      // consumed by all later kernels

    if (bid < 1){
        // ---- ranges ----
        int b = tid;
        int lo = 0, hi = N_NODES;
        while (lo < hi){ int mid = (lo + hi) >> 1; if (batch[mid] < b) lo = mid + 1; else hi = mid; }
        g_gstart[b] = lo;
        if (b == 0) g_gstart[NB] = N_NODES;
    } else if (bid < 257){
        // ---- edge count (g_deg pre-zeroed invariant) ----
        int e = (bid - 1)*256 + tid;
        atomicAdd(&g_deg[ei[N_EDGES + e]], 1);
    } else {
        // ---- proj78 ----
        for (int i = tid; i < 78*32; i += 256) sW1[i] = LD(g1W1, i, F);
        int nodeBase = (bid - 257)*8;
        for (int i = tid; i < 8*78; i += 256){
            int ln = i / 78, f = i - ln*78;
            sx[ln][f] = LD(x, (nodeBase + ln)*78 + f, F);
        }
        __syncthreads();
        int ln = tid >> 5, j = tid & 31;
        float a = 0.f;
        #pragma unroll 6
        for (int i = 0; i < 78; i++) a += sx[ln][i] * sW1[i*32 + j];
        g_hA[(nodeBase + ln)*32 + j] = a;
    }
}

// ---- CSR scan: consumes g_deg, re-zeroes it for the next iteration ----
__global__ __launch_bounds__(1024) void k_scan(){                            // 1 block
    __shared__ int part[1024];
    int t = threadIdx.x;
    int base = t*16;
    int s = 0;
    #pragma unroll
    for (int i = 0; i < 16; i++) s += g_deg[base + i];
    part[t] = s;
    __syncthreads();
    for (int off = 1; off < 1024; off <<= 1){
        int v = (t >= off) ? part[t - off] : 0;
        __syncthreads();
        part[t] += v;
        __syncthreads();
    }
    int run = (t == 0) ? 0 : part[t - 1];
    for (int i = 0; i < 16; i++){
        g_rowptr[base + i] = run;
        g_cur[base + i] = run;
        run += g_deg[base + i];
        g_deg[base + i] = 0;         // restore the zero invariant for k_prep
    }
    if (t == 1023) g_rowptr[N_NODES] = run;
}
__global__ void k_fill(const int* __restrict__ ei){
    int e = blockIdx.x*256 + threadIdx.x;                                    // grid 256
    int d = ei[N_EDGES + e];
    int slot = atomicAdd(&g_cur[d], 1);
    g_csrc[slot] = ei[e];
}

// cooperative edge gather: 32 lanes of a node load up to 32 indices at once,
// broadcast via shuffle -> feature gathers become independent (same sum order)
__device__ __forceinline__ float csr_gather(const float* hin, int n, int j){
    int rs = g_rowptr[n];
    int deg = g_rowptr[n + 1] - rs;
    float agg = 0.f;
    for (int base = 0; base < deg; base += 32){
        int cnt = deg - base; if (cnt > 32) cnt = 32;
        int myidx = (j < cnt) ? g_csrc[rs + base + j] : 0;
        for (int e = 0; e < cnt; e++){
            int src = __shfl(myidx, e, 32);
            agg += hin[src*32 + j];
        }
    }
    return agg;
}

// hA -> hB, PLUS 356 extra blocks doing conv-branch prep (wpack/P/wsum/xcm0)
#define GIN1B_GIN 2048
#define GIN1B_EXTRA 356      // 256 wpack + 52 P + 16 wsum + 32 xcm0

__global__ __launch_bounds__(256) void k_gin1b(
    const void* b1, const void* W2, const void* b2,
    const void* bng, const void* bnb, const void* bnm, const void* bnv,
    const void* embed, const void* c1W, const void* c2W, const void* c3W)
{
    const int F = g_isf32;
    int tid = threadIdx.x, bid = blockIdx.x;

    if (bid >= GIN1B_GIN){
        int t = bid - GIN1B_GIN;
        if (t < 256){
            // ---- wpack ----
            int idx = t*256 + tid;
            int sel = idx >> 15;
            int r = idx & 32767;
            int j = r & 7;
            int lane = (r >> 3) & 63;
            int hl = (r >> 9) & 1;
            int ogrp = (r >> 10) & 1;
            int ktg = r >> 11;
            int c = (lane >> 4)*8 + j;
            int o = ogrp*16 + (lane & 15);
            const void* Wt = sel ? c3W : c2W;
            float wv = LD(Wt, o*512 + c*16 + ktg, F);
            unsigned short h = f2b(wv);
            g_wf[sel][r] = hl ? f2b(wv - bb2f(h)) : h;
        } else if (t < 308){
            // ---- P table, k-fastest lane remap (coalesced c1W reads) ----
            int idx = (t - 256)*256 + tid;          // 0..13311 (52*256 exact)
            int k = idx & 15, o = (idx >> 4) & 31, tt = idx >> 9;
            float acc = 0.f;
            for (int c = 0; c < 128; c++)
                acc += LD(embed, tt*128 + c, F) * LD(c1W, o*4096 + c*16 + k, F);
            g_P[(k*26 + tt)*32 + o] = acc;
        } else if (t < 324){
            // ---- wsum ----
            int idx = (t - 308)*256 + tid;
            int o = idx >> 7, c = idx & 127;
            float a = 0.f;
            #pragma unroll
            for (int k = 0; k < 16; k++) a += LD(c1W, o*4096 + (128 + c)*16 + k, F);
            g_wsum[o*128 + c] = a;
        } else {
            // ---- xcm zero ----
            int i = (t - 324)*256 + tid;            // 32*256 = 8192 exact
            g_xcm[i] = 0.f;
        }
        return;
    }

    __shared__ float sW2[32*32];
    __shared__ float sb1[32], sb2[32], sA[32], sB[32];
    __shared__ float st[8][32];
    for (int i = tid; i < 1024; i += 256) sW2[i] = LD(W2, i, F);
    if (tid < 32){
        sb1[tid] = LD(b1, tid, F); sb2[tid] = LD(b2, tid, F);
        float inv = LD(bng, tid, F) * rsqrtf(LD(bnv, tid, F) + BN_EPS);
        sA[tid] = inv;
        sB[tid] = LD(bnb, tid, F) - LD(bnm, tid, F) * inv;
    }
    __syncthreads();
    int ln = tid >> 5, j = tid & 31;
    int n = bid*8 + ln;
    float agg = csr_gather(g_hA, n, j);
    st[ln][j] = fmaxf(g_hA[n*32 + j] + agg + sb1[j], 0.f);
    __syncthreads();
    float t2 = sb2[j];
    #pragma unroll
    for (int i = 0; i < 32; i++) t2 += st[ln][i] * sW2[i*32 + j];
    t2 = fmaxf(t2, 0.f);
    g_hB[n*32 + j] = t2 * sA[j] + sB[j];
}

// alternating hB->hA (l even) / hA->hB (l odd)
__global__ __launch_bounds__(256) void k_gin32L(
    const void* W1, const void* b1, const void* W2, const void* b2,
    const void* bng, const void* bnb, const void* bnm, const void* bnv, int l)
{
    const int F = g_isf32;
    const float* hin = (l & 1) ? g_hA : g_hB;
    float* hout = (l & 1) ? g_hB : g_hA;
    const int oW = l*1024, ob = l*32, obn = (l+1)*32;
    __shared__ float sW1[32*32], sW2[32*32];
    __shared__ float sb1[32], sb2[32], sA[32], sB[32];
    __shared__ float sh[8][32], st[8][32];
    int tid = threadIdx.x;
    for (int i = tid; i < 1024; i += 256){ sW1[i] = LD(W1, oW + i, F); sW2[i] = LD(W2, oW + i, F); }
    if (tid < 32){
        sb1[tid] = LD(b1, ob + tid, F); sb2[tid] = LD(b2, ob + tid, F);
        float inv = LD(bng, obn + tid, F) * rsqrtf(LD(bnv, obn + tid, F) + BN_EPS);
        sA[tid] = inv;
        sB[tid] = LD(bnb, obn + tid, F) - LD(bnm, obn + tid, F) * inv;
    }
    int ln = tid >> 5, j = tid & 31;
    int n = blockIdx.x*8 + ln;
    float agg = csr_gather(hin, n, j);
    sh[ln][j] = hin[n*32 + j] + agg;
    __syncthreads();
    float t1 = sb1[j];
    #pragma unroll
    for (int i = 0; i < 32; i++) t1 += sh[ln][i] * sW1[i*32 + j];
    st[ln][j] = fmaxf(t1, 0.f);
    __syncthreads();
    float t2 = sb2[j];
    #pragma unroll
    for (int i = 0; i < 32; i++) t2 += st[ln][i] * sW2[i*32 + j];
    t2 = fmaxf(t2, 0.f);
    hout[n*32 + j] = t2 * sA[j] + sB[j];
}

// fused pool (range-based) + xd + xdbias; final h lives in g_hB
__global__ __launch_bounds__(256) void k_poolxd(const void* W, const void* bias,
                                                const void* c1b){
    const int F = g_isf32;
    __shared__ float red[8][32];
    __shared__ float sxd[128];
    int b = blockIdx.x, tid = threadIdx.x;
    int j = tid & 31, sub = tid >> 5;
    int s = g_gstart[b], e = g_gstart[b + 1];
    float a = 0.f;
    for (int n = s + sub; n < e; n += 8) a += g_hB[n*32 + j];
    red[sub][j] = a;
    __syncthreads();
    if (sub == 0){
        red[0][j] = red[0][j] + red[1][j] + red[2][j] + red[3][j]
                  + red[4][j] + red[5][j] + red[6][j] + red[7][j];
    }
    __syncthreads();
    if (tid < 128){
        float acc = LD(bias, tid, F);
        #pragma unroll
        for (int i = 0; i < 32; i++) acc += red[0][i] * LD(W, i*128 + tid, F);
        float xdv = fmaxf(acc, 0.f);
        g_xd[b*128 + tid] = xdv;
        sxd[tid] = xdv;
    }
    __syncthreads();
    if (tid < 32){
        float a2 = LD(c1b, tid, F);
        for (int c = 0; c < 128; c++) a2 += sxd[c] * g_wsum[tid*128 + c];
        g_xdb[b*32 + tid] = a2;
    }
}

// ---------------- FUSED conv1+conv2+conv3 -------------------------------
// This round: LDS-traffic attack. Waves remapped (ogrp,part) -> tile-only;
// each wave computes BOTH ogrps' outputs from ONE ah/al LDS read (the two
// ogrp waves previously read identical A-fragments -> 2x redundant LDS
// traffic; LDS was the dominant pipe at ~50% busy). Weight lines are
// L1-resident so the doubled per-wave weight stream is ~free. Per-output
// accumulation order (ktg ascending; ah*bh, ah*bl, al*bh) unchanged ->
// bit-identical results.

#define FT_W 128
#define C1R 160      // need rows 0..158
#define C2R 144      // need rows 0..142 read, 0..143 written
#define CPAD 40      // 80 B rows: 16B-aligned, uniform 8-lane/bank-group (b128 floor)
#define STGN 176

#define MFMA_BF16 __builtin_amdgcn_mfma_f32_16x16x32_bf16

__global__ __launch_bounds__(512, 6) void k_cfuse(
    const int* __restrict__ target,
    const void* g, const void* be, const void* m, const void* v,   // cbn* stacked [3][32]
    const void* c2b, const void* c3b)
{
    const int F = g_isf32;
    __shared__ int stg[STGN];
    __shared__ __attribute__((aligned(16))) unsigned short sC1h[C1R*CPAD]; // 12800 B
    __shared__ __attribute__((aligned(16))) unsigned short sC1l[C1R*CPAD]; // 12800 B
    __shared__ __attribute__((aligned(16))) unsigned short sC2h[C2R*CPAD]; // 11520 B
    __shared__ __attribute__((aligned(16))) unsigned short sC2l[C2R*CPAD]; // 11520 B
    __shared__ float sxb[32], sA1[32], sB1[32], sSc2[32], sOf2[32], sSc3[32], sOf3[32];
    int b = blockIdx.x >> 3;
    int tile = blockIdx.x & 7;
    int wbase = tile * FT_W;
    int tid = threadIdx.x;

    for (int i = tid; i < STGN; i += 512){
        int gi = wbase + i;
        stg[i] = (gi < LSEQ) ? target[b*LSEQ + gi] : 0;
    }
    if (tid < 32){
        sxb[tid] = g_xdb[b*32 + tid];
        float i1 = LD(g, tid, F) * rsqrtf(LD(v, tid, F) + BN_EPS);
        sA1[tid] = i1;
        sB1[tid] = LD(be, tid, F) - LD(m, tid, F) * i1;
        float i2 = LD(g, 32 + tid, F) * rsqrtf(LD(v, 32 + tid, F) + BN_EPS);
        sSc2[tid] = i2;
        sOf2[tid] = LD(be, 32 + tid, F) + (LD(c2b, tid, F) - LD(m, 32 + tid, F)) * i2;
        float i3 = LD(g, 64 + tid, F) * rsqrtf(LD(v, 64 + tid, F) + BN_EPS);
        sSc3[tid] = i3;
        sOf3[tid] = LD(be, 64 + tid, F) + (LD(c3b, tid, F) - LD(m, 64 + tid, F)) * i3;
    }
    __syncthreads();

    // ---- Phase A: conv1, TWO rows in flight (frozen from r4) ----
    {
        int o = tid & 31, rsub = tid >> 5;          // rsub 0..15
        float iA = sA1[o], iB = sB1[o], xb = sxb[o];
        for (int r0 = rsub; r0 < C1R; r0 += 32){
            int r1 = r0 + 16;                       // < 160 always
            float a0 = xb, a1 = xb;
            #pragma unroll
            for (int k = 0; k < 16; k++){
                a0 += g_P[(k*26 + stg[r0 + k])*32 + o];
                a1 += g_P[(k*26 + stg[r1 + k])*32 + o];
            }
            float v0 = (wbase + r0 < W1O) ? fmaxf(a0 * iA + iB, 0.f) : 0.f;
            float v1 = (wbase + r1 < W1O) ? fmaxf(a1 * iA + iB, 0.f) : 0.f;
            unsigned short h0 = f2b(v0), h1 = f2b(v1);
            sC1h[r0*CPAD + o] = h0;
            sC1l[r0*CPAD + o] = f2b(v0 - bb2f(h0));
            sC1h[r1*CPAD + o] = h1;
            sC1l[r1*CPAD + o] = f2b(v1 - bb2f(h1));
        }
    }
    __syncthreads();

    int lane = tid & 63;
    int wv = tid >> 6;                  // 0..7 = m-tile owner
    int ml = lane & 15, quad = lane >> 4;

    // ---- Phase B: conv2 rows [0,144); wave wv owns m-tile wv (+ tile 8 on
    // wave 0), computing BOTH ogrps from one ah/al read ----
    {
        const s8v* wf0 = (const s8v*)&g_wf[0][0] + lane;          // ogrp0
        const s8v* wf1 = (const s8v*)&g_wf[0][0] + 128 + lane;    // ogrp1
        int has2 = (wv == 0);           // wave 0 also owns m-tile 8
        f4v a00 = (f4v){0.f,0.f,0.f,0.f}, a01 = (f4v){0.f,0.f,0.f,0.f};
        f4v a10 = (f4v){0.f,0.f,0.f,0.f}, a11 = (f4v){0.f,0.f,0.f,0.f};
        s8v nh0 = wf0[0], nl0 = wf0[64];
        s8v nh1 = wf1[0], nl1 = wf1[64];
        for (int ktg = 0; ktg < 16; ktg++){
            s8v bh0 = nh0, bl0 = nl0, bh1 = nh1, bl1 = nl1;
            if (ktg < 15){
                nh0 = wf0[(ktg+1)*256]; nl0 = wf0[(ktg+1)*256 + 64];
                nh1 = wf1[(ktg+1)*256]; nl1 = wf1[(ktg+1)*256 + 64];
            }
            {
                int row = wv*16 + ml + ktg;                 // <= 7*16+15+15=142
                int aidx = row*CPAD + quad*8;
                s8v ah = *(const s8v*)&sC1h[aidx];
                s8v al = *(const s8v*)&sC1l[aidx];
                a00 = MFMA_BF16(ah, bh0, a00, 0, 0, 0);
                a00 = MFMA_BF16(ah, bl0, a00, 0, 0, 0);
                a00 = MFMA_BF16(al, bh0, a00, 0, 0, 0);
                a01 = MFMA_BF16(ah, bh1, a01, 0, 0, 0);
                a01 = MFMA_BF16(ah, bl1, a01, 0, 0, 0);
                a01 = MFMA_BF16(al, bh1, a01, 0, 0, 0);
            }
            if (has2){
                int row = 128 + ml + ktg;                   // <= 158
                int aidx = row*CPAD + quad*8;
                s8v ah = *(const s8v*)&sC1h[aidx];
                s8v al = *(const s8v*)&sC1l[aidx];
                a10 = MFMA_BF16(ah, bh0, a10, 0, 0, 0);
                a10 = MFMA_BF16(ah, bl0, a10, 0, 0, 0);
                a10 = MFMA_BF16(al, bh0, a10, 0, 0, 0);
                a11 = MFMA_BF16(ah, bh1, a11, 0, 0, 0);
                a11 = MFMA_BF16(ah, bl1, a11, 0, 0, 0);
                a11 = MFMA_BF16(al, bh1, a11, 0, 0, 0);
            }
        }
        float sc0 = sSc2[ml],      of0 = sOf2[ml];          // ogrp0: oo=ml
        float sc1 = sSc2[16 + ml], of1 = sOf2[16 + ml];     // ogrp1: oo=16+ml
        {
            float y00[4] = {a00.x, a00.y, a00.z, a00.w};
            float y01[4] = {a01.x, a01.y, a01.z, a01.w};
            #pragma unroll
            for (int rr = 0; rr < 4; rr++){
                int row = wv*16 + quad*4 + rr;              // <= 127
                float u0 = fmaxf(y00[rr]*sc0 + of0, 0.f);
                unsigned short h0 = f2b(u0);
                sC2h[row*CPAD + ml] = h0;
                sC2l[row*CPAD + ml] = f2b(u0 - bb2f(h0));
                float u1 = fmaxf(y01[rr]*sc1 + of1, 0.f);
                unsigned short h1 = f2b(u1);
                sC2h[row*CPAD + 16 + ml] = h1;
                sC2l[row*CPAD + 16 + ml] = f2b(u1 - bb2f(h1));
            }
        }
        if (has2){
            float y10[4] = {a10.x, a10.y, a10.z, a10.w};
            float y11[4] = {a11.x, a11.y, a11.z, a11.w};
            #pragma unroll
            for (int rr = 0; rr < 4; rr++){
                int row = 128 + quad*4 + rr;                // <= 143
                float u0 = fmaxf(y10[rr]*sc0 + of0, 0.f);
                unsigned short h0 = f2b(u0);
                sC2h[row*CPAD + ml] = h0;
                sC2l[row*CPAD + ml] = f2b(u0 - bb2f(h0));
                float u1 = fmaxf(y11[rr]*sc1 + of1, 0.f);
                unsigned short h1 = f2b(u1);
                sC2h[row*CPAD + 16 + ml] = h1;
                sC2l[row*CPAD + 16 + ml] = f2b(u1 - bb2f(h1));
            }
        }
    }
    __syncthreads();

    // ---- Phase C: conv3; wave wv owns m-tile wv, both ogrps ----
    {
        const s8v* wf0 = (const s8v*)&g_wf[1][0] + lane;          // ogrp0
        const s8v* wf1 = (const s8v*)&g_wf[1][0] + 128 + lane;    // ogrp1
        f4v c0 = (f4v){0.f,0.f,0.f,0.f}, c1 = (f4v){0.f,0.f,0.f,0.f};
        s8v nh0 = wf0[0], nl0 = wf0[64];
        s8v nh1 = wf1[0], nl1 = wf1[64];
        for (int ktg = 0; ktg < 16; ktg++){
            s8v bh0 = nh0, bl0 = nl0, bh1 = nh1, bl1 = nl1;
            if (ktg < 15){
                nh0 = wf0[(ktg+1)*256]; nl0 = wf0[(ktg+1)*256 + 64];
                nh1 = wf1[(ktg+1)*256]; nl1 = wf1[(ktg+1)*256 + 64];
            }
            int row = wv*16 + ml + ktg;                     // <= 142
            int aidx = row*CPAD + quad*8;
            s8v ah = *(const s8v*)&sC2h[aidx];
            s8v al = *(const s8v*)&sC2l[aidx];
            c0 = MFMA_BF16(ah, bh0, c0, 0, 0, 0);
            c0 = MFMA_BF16(ah, bl0, c0, 0, 0, 0);
            c0 = MFMA_BF16(al, bh0, c0, 0, 0, 0);
            c1 = MFMA_BF16(ah, bh1, c1, 0, 0, 0);
            c1 = MFMA_BF16(ah, bl1, c1, 0, 0, 0);
            c1 = MFMA_BF16(al, bh1, c1, 0, 0, 0);
        }
        float sc0 = sSc3[ml],      of0 = sOf3[ml];
        float sc1 = sSc3[16 + ml], of1 = sOf3[16 + ml];
        int w0 = wbase + wv*16 + quad*4;
        if (w0 < W3O){
            float p0 = fmaxf(c0.x*sc0 + of0, 0.f);
            float p1 = fmaxf(c0.y*sc0 + of0, 0.f);
            float p2 = fmaxf(c0.z*sc0 + of0, 0.f);
            float p3 = fmaxf(c0.w*sc0 + of0, 0.f);
            float mx = p0;
            if (w0+1 < W3O) mx = fmaxf(mx, p1);
            if (w0+2 < W3O) mx = fmaxf(mx, p2);
            if (w0+3 < W3O) mx = fmaxf(mx, p3);
            atomicMax((int*)&g_xcm[b*32 + ml], __float_as_int(mx));
            float q0 = fmaxf(c1.x*sc1 + of1, 0.f);
            float q1 = fmaxf(c1.y*sc1 + of1, 0.f);
            float q2 = fmaxf(c1.z*sc1 + of1, 0.f);
            float q3 = fmaxf(c1.w*sc1 + of1, 0.f);
            float my = q0;
            if (w0+1 < W3O) my = fmaxf(my, q1);
            if (w0+2 < W3O) my = fmaxf(my, q2);
            if (w0+3 < W3O) my = fmaxf(my, q3);
            atomicMax((int*)&g_xcm[b*32 + 16 + ml], __float_as_int(my));
        }
    }
}

// ---------------- fused FC tail: 2 graphs/block, shared weight loads -------
// Each weight element loaded once, applied to both graphs' accumulators ->
// halves the redundant fc1W/fc2W L2 stream. Per-graph sum order unchanged.

__global__ __launch_bounds__(1024) void k_tail(
    const void* fcxcW, const void* fcxcb,
    const void* bg, const void* bb, const void* bm, const void* bv,
    const void* fc1W, const void* fc1b,
    const void* fc2W, const void* fc2b,
    const void* outW, const void* outb, void* out)
{
    const int F = g_isf32;
    __shared__ float sz0[256], sz1[256];
    __shared__ float z1s0[1024], z1s1[1024];
    __shared__ float sp0[4][256], sp1[4][256];
    int b0 = blockIdx.x*2, b1 = b0 + 1, t = threadIdx.x;
    if (t < 128){
        sz0[t] = g_xd[b0*128 + t];
        sz1[t] = g_xd[b1*128 + t];
    } else if (t < 256){
        int j = t - 128;
        float a0 = LD(fcxcb, j, F), a1 = a0;
        #pragma unroll
        for (int i = 0; i < 32; i++){
            float w = LD(fcxcW, i*128 + j, F);
            a0 += g_xcm[b0*32 + i] * w;
            a1 += g_xcm[b1*32 + i] * w;
        }
        float inv = LD(bg, j, F) * rsqrtf(LD(bv, j, F) + BN_EPS);
        float bm_ = LD(bm, j, F), bb_ = LD(bb, j, F);
        sz0[t] = fmaxf((a0 - bm_) * inv + bb_, 0.f);
        sz1[t] = fmaxf((a1 - bm_) * inv + bb_, 0.f);
    }
    __syncthreads();
    {
        float a0 = LD(fc1b, t, F), a1 = a0;
        for (int i = 0; i < 256; i++){
            float w = LD(fc1W, i*1024 + t, F);
            a0 += sz0[i] * w;
            a1 += sz1[i] * w;
        }
        z1s0[t] = fmaxf(a0, 0.f);
        z1s1[t] = fmaxf(a1, 0.f);
    }
    __syncthreads();
    int j = t & 255, kq = t >> 8;
    {
        float a20 = 0.f, a21 = 0.f;
        #pragma unroll 8
        for (int i = 0; i < 256; i++){
            float w = LD(fc2W, (kq*256 + i)*256 + j, F);
            a20 += z1s0[kq*256 + i] * w;
            a21 += z1s1[kq*256 + i] * w;
        }
        sp0[kq][j] = a20;
        sp1[kq][j] = a21;
    }
    __syncthreads();
    if (t < 256){
        float bias = LD(fc2b, t, F), ow = LD(outW, t, F);
        float z20 = fmaxf(sp0[0][t] + sp0[1][t] + sp0[2][t] + sp0[3][t] + bias, 0.f);
        float z21 = fmaxf(sp1[0][t] + sp1[1][t] + sp1[2][t] + sp1[3][t] + bias, 0.f);
        sp0[0][t] = z20 * ow;
        sp1[0][t] = z21 * ow;
    }
    __syncthreads();
    for (int s = 128; s > 0; s >>= 1){
        if (t < s){
            sp0[0][t] += sp0[0][t + s];
            sp1[0][t] += sp1[0][t + s];
        }
        __syncthreads();
    }
    if (t == 0){
        float ob = LD(outb, 0, F);
        float r0 = sp0[0][0] + ob;
        float r1 = sp1[0][0] + ob;
        if (F){ ((float*)out)[b0] = r0; ((float*)out)[b1] = r1; }
        else  { ((bf16*)out)[b0] = __float2bfloat16(r0);
                ((bf16*)out)[b1] = __float2bfloat16(r1); }
    }
}

// ---------------- launch ----------------

extern "C" void kernel_launch(void* const* d_in, const int* in_sizes, int n_in,
                              void* d_out, int out_size, void* d_ws, size_t ws_size,
                              hipStream_t stream)
{
    (void)in_sizes; (void)n_in; (void)out_size; (void)d_ws; (void)ws_size;
    const void* x      = d_in[0];
    const int*  ei     = (const int*)d_in[1];
    const int*  batch  = (const int*)d_in[2];
    const int*  target = (const int*)d_in[3];
    const void* g1W1 = d_in[4];  const void* g1b1 = d_in[5];
    const void* g1W2 = d_in[6];  const void* g1b2 = d_in[7];
    const void* gW1  = d_in[8];  const void* gb1  = d_in[9];
    const void* gW2  = d_in[10]; const void* gb2  = d_in[11];
    const void* bng  = d_in[12]; const void* bnb  = d_in[13];
    const void* bnm  = d_in[14]; const void* bnv  = d_in[15];
    const void* fcxdW = d_in[16]; const void* fcxdb = d_in[17];
    const void* embed = d_in[18];
    const void* c1W = d_in[19]; const void* c1b = d_in[20];
    const void* c2W = d_in[21]; const void* c2b = d_in[22];
    const void* c3W = d_in[23]; const void* c3b = d_in[24];
    const void* cbng = d_in[25]; const void* cbnb = d_in[26];
    const void* cbnm = d_in[27]; const void* cbnv = d_in[28];
    const void* fcxcW = d_in[29]; const void* fcxcb = d_in[30];
    const void* bnfcg = d_in[31]; const void* bnfcb = d_in[32];
    const void* bnfcm = d_in[33]; const void* bnfcv = d_in[34];
    const void* fc1W = d_in[35]; const void* fc1b = d_in[36];
    const void* fc2W = d_in[37]; const void* fc2b = d_in[38];
    const void* outW = d_in[39]; const void* outb = d_in[40];

    // ---- prep: dtype+ranges+count+proj78 (GIN prerequisites only) ----
    k_prep<<<PREP_BLOCKS, 256, 0, stream>>>(x, ei, batch, g1W1);
    // ---- CSR finish ----
    k_scan<<<1, 1024, 0, stream>>>();
    k_fill<<<N_EDGES/256, 256, 0, stream>>>(ei);
    // ---- GIN chain; gin1b also carries wpack/P/wsum/xcm0 in 356 extra blocks ----
    k_gin1b<<<GIN1B_GIN + GIN1B_EXTRA, 256, 0, stream>>>(
        g1b1, g1W2, g1b2, bng, bnb, bnm, bnv, embed, c1W, c2W, c3W);
    for (int l = 0; l < 4; l++){
        k_gin32L<<<N_NODES/8, 256, 0, stream>>>(gW1, gb1, gW2, gb2,
                                                bng, bnb, bnm, bnv, l);
    }
    // ---- pool+xd+xdbias fused ----
    k_poolxd<<<NB, 256, 0, stream>>>(fcxdW, fcxdb, c1b);
    // ---- FUSED conv chain (shared-A dual-ogrp waves) ----
    k_cfuse<<<NB*8, 512, 0, stream>>>(target, cbng, cbnb, cbnm, cbnv, c2b, c3b);
    // ---- fused FC tail: 2 graphs/block ----
    k_tail<<<NB/2, 1024, 0, stream>>>(fcxcW, fcxcb, bnfcg, bnfcb, bnfcm, bnfcv,
                                      fc1W, fc1b, fc2W, fc2b, outW, outb, d_out);
}

// Round 7
// 414.435 us; speedup vs baseline: 1.0304x; 1.0304x over previous
//
#include <hip/hip_runtime.h>
#include <hip/hip_bf16.h>

typedef __hip_bfloat16 bf16;
__device__ __forceinline__ float b2f(bf16 v){ return __bfloat162float(v); }

typedef __attribute__((ext_vector_type(8))) short s8v;
typedef __attribute__((ext_vector_type(4))) float f4v;

#define N_NODES 16384
#define N_EDGES 65536
#define NB 256
#define LSEQ 1000
#define BN_EPS 1e-5f
#define W1O 985
#define W2O 970
#define W3O 955

// ---- dtype flag: 1 if float inputs are f32, 0 if bf16 (measured: f32 on this harness) ----
__device__ int g_isf32;

__device__ __forceinline__ float LD(const void* p, int i, int f){
    return f ? ((const float*)p)[i] : b2f(((const bf16*)p)[i]);
}

// f32 -> bf16 bits, round-to-nearest-even
__device__ __forceinline__ unsigned short f2b(float x){
    unsigned u = __float_as_uint(x);
    return (unsigned short)((u + 0x7FFFu + ((u >> 16) & 1u)) >> 16);
}
__device__ __forceinline__ float bb2f(unsigned short h){
    return __uint_as_float(((unsigned)h) << 16);
}

// ---- intermediates in device globals ----
__device__ float g_hA[N_NODES*32];
__device__ float g_hB[N_NODES*32];
__device__ float g_P[16*26*32];
__device__ float g_wsum[32*128];
__device__ float g_xcm[NB*32];
// pre-packed conv weights in per-lane B-FRAGMENT order (s8v granularity):
// s8v index = ktg*256 + ogrp*128 + hl*64 + lane
__device__ __attribute__((aligned(16))) unsigned short g_wf[2][32768];
// CSR of the (fixed) edge list, destination-major
// INVARIANT: g_deg is zero at k_prep entry (zero-init at load; k_scan re-zeroes
// it after consuming it each iteration) -> k_count can run inside k_prep.
__device__ int g_deg[N_NODES];
__device__ int g_cur[N_NODES];
__device__ int g_rowptr[N_NODES + 1];
__device__ int g_csrc[N_EDGES];
__device__ int g_gstart[NB + 1];     // per-graph node ranges (batch is sorted)

// ================= PREP KERNEL (GIN-chain prerequisites only) =============
#define PREP_BLOCKS 2305

__global__ __launch_bounds__(256) void k_prep(
    const void* x, const int* __restrict__ ei, const int* __restrict__ batch,
    const void* g1W1)
{
    __shared__ float sW1[78*32];
    __shared__ float sx[8][78];
    __shared__ int s_cnt;
    int tid = threadIdx.x, bid = blockIdx.x;

    // per-block dtype detect (same statistic as legacy k_dtype)
    if (tid == 0) s_cnt = 0;
    __syncthreads();
    {
        const unsigned short* u = (const unsigned short*)x;
        int bad = 0;
        for (int i = tid; i < 512; i += 256){
            unsigned short h = u[i];
            int ex = (h >> 7) & 0xFF;
            if (!(h == 0 || (ex >= 96 && ex <= 142))) bad++;
        }
        if (bad) atomicAdd(&s_cnt, bad);
    }
    __syncthreads();
    const int F = (s_cnt > 50) ? 1 : 0;
    if (bid == 0 && tid == 0) g_isf32 = F;      // consumed by all later kernels

    if (bid < 1){
        // ---- ranges ----
        int b = tid;
        int lo = 0, hi = N_NODES;
        while (lo < hi){ int mid = (lo + hi) >> 1; if (batch[mid] < b) lo = mid + 1; else hi = mid; }
        g_gstart[b] = lo;
        if (b == 0) g_gstart[NB] = N_NODES;
    } else if (bid < 257){
        // ---- edge count (g_deg pre-zeroed invariant) ----
        int e = (bid - 1)*256 + tid;
        atomicAdd(&g_deg[ei[N_EDGES + e]], 1);
    } else {
        // ---- proj78 ----
        for (int i = tid; i < 78*32; i += 256) sW1[i] = LD(g1W1, i, F);
        int nodeBase = (bid - 257)*8;
        for (int i = tid; i < 8*78; i += 256){
            int ln = i / 78, f = i - ln*78;
            sx[ln][f] = LD(x, (nodeBase + ln)*78 + f, F);
        }
        __syncthreads();
        int ln = tid >> 5, j = tid & 31;
        float a = 0.f;
        #pragma unroll 6
        for (int i = 0; i < 78; i++) a += sx[ln][i] * sW1[i*32 + j];
        g_hA[(nodeBase + ln)*32 + j] = a;
    }
}

// ---- CSR scan: consumes g_deg, re-zeroes it for the next iteration ----
__global__ __launch_bounds__(1024) void k_scan(){                            // 1 block
    __shared__ int part[1024];
    int t = threadIdx.x;
    int base = t*16;
    int s = 0;
    #pragma unroll
    for (int i = 0; i < 16; i++) s += g_deg[base + i];
    part[t] = s;
    __syncthreads();
    for (int off = 1; off < 1024; off <<= 1){
        int v = (t >= off) ? part[t - off] : 0;
        __syncthreads();
        part[t] += v;
        __syncthreads();
    }
    int run = (t == 0) ? 0 : part[t - 1];
    for (int i = 0; i < 16; i++){
        g_rowptr[base + i] = run;
        g_cur[base + i] = run;
        run += g_deg[base + i];
        g_deg[base + i] = 0;         // restore the zero invariant for k_prep
    }
    if (t == 1023) g_rowptr[N_NODES] = run;
}
__global__ void k_fill(const int* __restrict__ ei){
    int e = blockIdx.x*256 + threadIdx.x;                                    // grid 256
    int d = ei[N_EDGES + e];
    int slot = atomicAdd(&g_cur[d], 1);
    g_csrc[slot] = ei[e];
}

// cooperative edge gather: 32 lanes of a node load up to 32 indices at once,
// broadcast via shuffle -> feature gathers become independent (same sum order)
__device__ __forceinline__ float csr_gather(const float* hin, int n, int j){
    int rs = g_rowptr[n];
    int deg = g_rowptr[n + 1] - rs;
    float agg = 0.f;
    for (int base = 0; base < deg; base += 32){
        int cnt = deg - base; if (cnt > 32) cnt = 32;
        int myidx = (j < cnt) ? g_csrc[rs + base + j] : 0;
        for (int e = 0; e < cnt; e++){
            int src = __shfl(myidx, e, 32);
            agg += hin[src*32 + j];
        }
    }
    return agg;
}

// hA -> hB, PLUS 356 extra blocks doing conv-branch prep (wpack/P/wsum/xcm0)
#define GIN1B_GIN 2048
#define GIN1B_EXTRA 356      // 256 wpack + 52 P + 16 wsum + 32 xcm0

__global__ __launch_bounds__(256) void k_gin1b(
    const void* b1, const void* W2, const void* b2,
    const void* bng, const void* bnb, const void* bnm, const void* bnv,
    const void* embed, const void* c1W, const void* c2W, const void* c3W)
{
    const int F = g_isf32;
    int tid = threadIdx.x, bid = blockIdx.x;

    if (bid >= GIN1B_GIN){
        int t = bid - GIN1B_GIN;
        if (t < 256){
            // ---- wpack ----
            int idx = t*256 + tid;
            int sel = idx >> 15;
            int r = idx & 32767;
            int j = r & 7;
            int lane = (r >> 3) & 63;
            int hl = (r >> 9) & 1;
            int ogrp = (r >> 10) & 1;
            int ktg = r >> 11;
            int c = (lane >> 4)*8 + j;
            int o = ogrp*16 + (lane & 15);
            const void* Wt = sel ? c3W : c2W;
            float wv = LD(Wt, o*512 + c*16 + ktg, F);
            unsigned short h = f2b(wv);
            g_wf[sel][r] = hl ? f2b(wv - bb2f(h)) : h;
        } else if (t < 308){
            // ---- P table, k-fastest lane remap (coalesced c1W reads) ----
            int idx = (t - 256)*256 + tid;          // 0..13311 (52*256 exact)
            int k = idx & 15, o = (idx >> 4) & 31, tt = idx >> 9;
            float acc = 0.f;
            for (int c = 0; c < 128; c++)
                acc += LD(embed, tt*128 + c, F) * LD(c1W, o*4096 + c*16 + k, F);
            g_P[(k*26 + tt)*32 + o] = acc;
        } else if (t < 324){
            // ---- wsum ----
            int idx = (t - 308)*256 + tid;
            int o = idx >> 7, c = idx & 127;
            float a = 0.f;
            #pragma unroll
            for (int k = 0; k < 16; k++) a += LD(c1W, o*4096 + (128 + c)*16 + k, F);
            g_wsum[o*128 + c] = a;
        } else {
            // ---- xcm zero ----
            int i = (t - 324)*256 + tid;            // 32*256 = 8192 exact
            g_xcm[i] = 0.f;
        }
        return;
    }

    __shared__ float sW2[32*32];
    __shared__ float sb1[32], sb2[32], sA[32], sB[32];
    __shared__ float st[8][32];
    for (int i = tid; i < 1024; i += 256) sW2[i] = LD(W2, i, F);
    if (tid < 32){
        sb1[tid] = LD(b1, tid, F); sb2[tid] = LD(b2, tid, F);
        float inv = LD(bng, tid, F) * rsqrtf(LD(bnv, tid, F) + BN_EPS);
        sA[tid] = inv;
        sB[tid] = LD(bnb, tid, F) - LD(bnm, tid, F) * inv;
    }
    __syncthreads();
    int ln = tid >> 5, j = tid & 31;
    int n = bid*8 + ln;
    float agg = csr_gather(g_hA, n, j);
    st[ln][j] = fmaxf(g_hA[n*32 + j] + agg + sb1[j], 0.f);
    __syncthreads();
    float t2 = sb2[j];
    #pragma unroll
    for (int i = 0; i < 32; i++) t2 += st[ln][i] * sW2[i*32 + j];
    t2 = fmaxf(t2, 0.f);
    g_hB[n*32 + j] = t2 * sA[j] + sB[j];
}

// alternating hB->hA (l even) / hA->hB (l odd)
__global__ __launch_bounds__(256) void k_gin32L(
    const void* W1, const void* b1, const void* W2, const void* b2,
    const void* bng, const void* bnb, const void* bnm, const void* bnv, int l)
{
    const int F = g_isf32;
    const float* hin = (l & 1) ? g_hA : g_hB;
    float* hout = (l & 1) ? g_hB : g_hA;
    const int oW = l*1024, ob = l*32, obn = (l+1)*32;
    __shared__ float sW1[32*32], sW2[32*32];
    __shared__ float sb1[32], sb2[32], sA[32], sB[32];
    __shared__ float sh[8][32], st[8][32];
    int tid = threadIdx.x;
    for (int i = tid; i < 1024; i += 256){ sW1[i] = LD(W1, oW + i, F); sW2[i] = LD(W2, oW + i, F); }
    if (tid < 32){
        sb1[tid] = LD(b1, ob + tid, F); sb2[tid] = LD(b2, ob + tid, F);
        float inv = LD(bng, obn + tid, F) * rsqrtf(LD(bnv, obn + tid, F) + BN_EPS);
        sA[tid] = inv;
        sB[tid] = LD(bnb, obn + tid, F) - LD(bnm, obn + tid, F) * inv;
    }
    int ln = tid >> 5, j = tid & 31;
    int n = blockIdx.x*8 + ln;
    float agg = csr_gather(hin, n, j);
    sh[ln][j] = hin[n*32 + j] + agg;
    __syncthreads();
    float t1 = sb1[j];
    #pragma unroll
    for (int i = 0; i < 32; i++) t1 += sh[ln][i] * sW1[i*32 + j];
    st[ln][j] = fmaxf(t1, 0.f);
    __syncthreads();
    float t2 = sb2[j];
    #pragma unroll
    for (int i = 0; i < 32; i++) t2 += st[ln][i] * sW2[i*32 + j];
    t2 = fmaxf(t2, 0.f);
    hout[n*32 + j] = t2 * sA[j] + sB[j];
}

// ---------------- FUSED conv1+conv2+conv3 -------------------------------
// Phases A/B/C restored VERBATIM to the round-4 version (best measured:
// 113.5 us; r6's shared-A remap halved LDS conflicts exactly as predicted
// but SLOWED the kernel 118->144 -> LDS is not the critical path; weight
// stream + chain interleave is. Reverted.)
// NEW this round: poolxd is eliminated as a dispatch; each cfuse block
// recomputes xdb inline (pool -> xd -> xdb, bit-identical order: stride-8
// partials, fixed 8-way sum, ascending GEMVs). ~2KB extra L2 reads/block.

#define FT_W 128
#define C1R 160      // need rows 0..158
#define C2R 144      // need rows 0..142 read, 0..143 written
#define CPAD 40      // 80 B rows: 16B-aligned, uniform 8-lane/bank-group (b128 floor)
#define STGN 176

__global__ __launch_bounds__(512, 6) void k_cfuse(
    const int* __restrict__ target,
    const void* g, const void* be, const void* m, const void* v,   // cbn* stacked [3][32]
    const void* c2b, const void* c3b,
    const void* fcxdW, const void* fcxdb, const void* c1b)
{
    const int F = g_isf32;
    __shared__ int stg[STGN];
    __shared__ __attribute__((aligned(16))) unsigned short sC1h[C1R*CPAD]; // 12800 B
    __shared__ __attribute__((aligned(16))) unsigned short sC1l[C1R*CPAD]; // 12800 B
    __shared__ __attribute__((aligned(16))) unsigned short sC2h[C2R*CPAD]; // 11520 B
    __shared__ __attribute__((aligned(16))) unsigned short sC2l[C2R*CPAD]; // 11520 B
    __shared__ float sxb[32], sA1[32], sB1[32], sSc2[32], sOf2[32], sSc3[32], sOf3[32];
    __shared__ float pred[8][32];      // pool partials (poolxd-inline)
    __shared__ float pxd[128];         // xd (poolxd-inline)
    int b = blockIdx.x >> 3;
    int tile = blockIdx.x & 7;
    int wbase = tile * FT_W;
    int tid = threadIdx.x;

    for (int i = tid; i < STGN; i += 512){
        int gi = wbase + i;
        stg[i] = (gi < LSEQ) ? target[b*LSEQ + gi] : 0;
    }
    if (tid < 32){
        float i1 = LD(g, tid, F) * rsqrtf(LD(v, tid, F) + BN_EPS);
        sA1[tid] = i1;
        sB1[tid] = LD(be, tid, F) - LD(m, tid, F) * i1;
        float i2 = LD(g, 32 + tid, F) * rsqrtf(LD(v, 32 + tid, F) + BN_EPS);
        sSc2[tid] = i2;
        sOf2[tid] = LD(be, 32 + tid, F) + (LD(c2b, tid, F) - LD(m, 32 + tid, F)) * i2;
        float i3 = LD(g, 64 + tid, F) * rsqrtf(LD(v, 64 + tid, F) + BN_EPS);
        sSc3[tid] = i3;
        sOf3[tid] = LD(be, 64 + tid, F) + (LD(c3b, tid, F) - LD(m, 64 + tid, F)) * i3;
    }
    // ---- inline xdb (exact poolxd math: stride-8 pool, 8-way sum, GEMVs) ----
    {
        int s = g_gstart[b], e = g_gstart[b + 1];
        if (tid < 256){
            int j = tid & 31, sub = tid >> 5;
            float a = 0.f;
            for (int n = s + sub; n < e; n += 8) a += g_hB[n*32 + j];
            pred[sub][j] = a;
        }
        __syncthreads();
        if (tid < 32){
            int j = tid;
            pred[0][j] = pred[0][j] + pred[1][j] + pred[2][j] + pred[3][j]
                       + pred[4][j] + pred[5][j] + pred[6][j] + pred[7][j];
        }
        __syncthreads();
        if (tid < 128){
            float acc = LD(fcxdb, tid, F);
            #pragma unroll
            for (int i = 0; i < 32; i++) acc += pred[0][i] * LD(fcxdW, i*128 + tid, F);
            pxd[tid] = fmaxf(acc, 0.f);
        }
        __syncthreads();
        if (tid < 32){
            float a2 = LD(c1b, tid, F);
            for (int c = 0; c < 128; c++) a2 += pxd[c] * g_wsum[tid*128 + c];
            sxb[tid] = a2;
        }
    }
    __syncthreads();

    // ---- Phase A: conv1, TWO rows in flight (frozen r4) ----
    {
        int o = tid & 31, rsub = tid >> 5;          // rsub 0..15
        float iA = sA1[o], iB = sB1[o], xb = sxb[o];
        for (int r0 = rsub; r0 < C1R; r0 += 32){
            int r1 = r0 + 16;                       // < 160 always
            float a0 = xb, a1 = xb;
            #pragma unroll
            for (int k = 0; k < 16; k++){
                a0 += g_P[(k*26 + stg[r0 + k])*32 + o];
                a1 += g_P[(k*26 + stg[r1 + k])*32 + o];
            }
            float v0 = (wbase + r0 < W1O) ? fmaxf(a0 * iA + iB, 0.f) : 0.f;
            float v1 = (wbase + r1 < W1O) ? fmaxf(a1 * iA + iB, 0.f) : 0.f;
            unsigned short h0 = f2b(v0), h1 = f2b(v1);
            sC1h[r0*CPAD + o] = h0;
            sC1l[r0*CPAD + o] = f2b(v0 - bb2f(h0));
            sC1h[r1*CPAD + o] = h1;
            sC1l[r1*CPAD + o] = f2b(v1 - bb2f(h1));
        }
    }
    __syncthreads();

    int lane = tid & 63;
    int wv = tid >> 6;                  // 0..7
    int ml = lane & 15, quad = lane >> 4;
    int ogrp = wv & 1;
    int part = wv >> 1;                 // 0..3
    int oo = ogrp*16 + ml;

    // ---- Phase B: conv2 rows [0,144); m-tiles mt = part + 4*i (frozen r4) ----
    {
        const s8v* wfb = (const s8v*)&g_wf[0][0] + ogrp*128 + lane;
        int nmt = (part == 0) ? 3 : 2;   // part0: mt 0,4,8 ; part p: mt p, p+4
        f4v acc[3];
        #pragma unroll
        for (int i = 0; i < 3; i++) acc[i] = (f4v){0.f,0.f,0.f,0.f};
        s8v bhA = wfb[0],   blA = wfb[64];
        s8v bhB = wfb[256], blB = wfb[320];
        for (int ktg = 0; ktg < 16; ktg += 2){
            s8v ch = bhA, cl = blA;
            if (ktg + 2 < 16){ bhA = wfb[(ktg+2)*256]; blA = wfb[(ktg+2)*256 + 64]; }
            #pragma unroll
            for (int i = 0; i < 3; i++){
                if (i < nmt){
                    int row = (part + 4*i)*16 + ml + ktg;       // <= 158
                    int aidx = row*CPAD + quad*8;
                    s8v ah = *(const s8v*)&sC1h[aidx];
                    s8v al = *(const s8v*)&sC1l[aidx];
                    acc[i] = __builtin_amdgcn_mfma_f32_16x16x32_bf16(ah, ch, acc[i], 0, 0, 0);
                    acc[i] = __builtin_amdgcn_mfma_f32_16x16x32_bf16(ah, cl, acc[i], 0, 0, 0);
                    acc[i] = __builtin_amdgcn_mfma_f32_16x16x32_bf16(al, ch, acc[i], 0, 0, 0);
                }
            }
            s8v dh = bhB, dl = blB;
            if (ktg + 3 < 16){ bhB = wfb[(ktg+3)*256]; blB = wfb[(ktg+3)*256 + 64]; }
            #pragma unroll
            for (int i = 0; i < 3; i++){
                if (i < nmt){
                    int row = (part + 4*i)*16 + ml + ktg + 1;   // <= 158
                    int aidx = row*CPAD + quad*8;
                    s8v ah = *(const s8v*)&sC1h[aidx];
                    s8v al = *(const s8v*)&sC1l[aidx];
                    acc[i] = __builtin_amdgcn_mfma_f32_16x16x32_bf16(ah, dh, acc[i], 0, 0, 0);
                    acc[i] = __builtin_amdgcn_mfma_f32_16x16x32_bf16(ah, dl, acc[i], 0, 0, 0);
                    acc[i] = __builtin_amdgcn_mfma_f32_16x16x32_bf16(al, dh, acc[i], 0, 0, 0);
                }
            }
        }
        float sc = sSc2[oo], of = sOf2[oo];
        #pragma unroll
        for (int i = 0; i < 3; i++){
            if (i < nmt){
                int mt = part + 4*i;
                f4v a = acc[i];
                float ys[4] = {a.x, a.y, a.z, a.w};
                #pragma unroll
                for (int rr = 0; rr < 4; rr++){
                    int row = mt*16 + quad*4 + rr;              // <= 143
                    float y = fmaxf(ys[rr]*sc + of, 0.f);
                    unsigned short h = f2b(y);
                    sC2h[row*CPAD + oo] = h;
                    sC2l[row*CPAD + oo] = f2b(y - bb2f(h));
                }
            }
        }
    }
    __syncthreads();

    // ---- Phase C: conv3 + maxpool epilogue (frozen r4) ----
    {
        const s8v* wfb = (const s8v*)&g_wf[1][0] + ogrp*128 + lane;
        f4v acc[2];
        #pragma unroll
        for (int i = 0; i < 2; i++) acc[i] = (f4v){0.f,0.f,0.f,0.f};
        s8v bhA = wfb[0],   blA = wfb[64];
        s8v bhB = wfb[256], blB = wfb[320];
        for (int ktg = 0; ktg < 16; ktg += 2){
            s8v ch = bhA, cl = blA;
            if (ktg + 2 < 16){ bhA = wfb[(ktg+2)*256]; blA = wfb[(ktg+2)*256 + 64]; }
            #pragma unroll
            for (int i = 0; i < 2; i++){
                int row = (part + 4*i)*16 + ml + ktg;           // <= 142
                int aidx = row*CPAD + quad*8;
                s8v ah = *(const s8v*)&sC2h[aidx];
                s8v al = *(const s8v*)&sC2l[aidx];
                acc[i] = __builtin_amdgcn_mfma_f32_16x16x32_bf16(ah, ch, acc[i], 0, 0, 0);
                acc[i] = __builtin_amdgcn_mfma_f32_16x16x32_bf16(ah, cl, acc[i], 0, 0, 0);
                acc[i] = __builtin_amdgcn_mfma_f32_16x16x32_bf16(al, ch, acc[i], 0, 0, 0);
            }
            s8v dh = bhB, dl = blB;
            if (ktg + 3 < 16){ bhB = wfb[(ktg+3)*256]; blB = wfb[(ktg+3)*256 + 64]; }
            #pragma unroll
            for (int i = 0; i < 2; i++){
                int row = (part + 4*i)*16 + ml + ktg + 1;       // <= 142
                int aidx = row*CPAD + quad*8;
                s8v ah = *(const s8v*)&sC2h[aidx];
                s8v al = *(const s8v*)&sC2l[aidx];
                acc[i] = __builtin_amdgcn_mfma_f32_16x16x32_bf16(ah, dh, acc[i], 0, 0, 0);
                acc[i] = __builtin_amdgcn_mfma_f32_16x16x32_bf16(ah, dl, acc[i], 0, 0, 0);
                acc[i] = __builtin_amdgcn_mfma_f32_16x16x32_bf16(al, dh, acc[i], 0, 0, 0);
            }
        }
        float sc = sSc3[oo], of = sOf3[oo];
        #pragma unroll
        for (int i = 0; i < 2; i++){
            int mt = part + 4*i;
            int w0 = wbase + mt*16 + quad*4;
            f4v a = acc[i];
            float y0 = fmaxf(a.x*sc + of, 0.f);
            float y1 = fmaxf(a.y*sc + of, 0.f);
            float y2 = fmaxf(a.z*sc + of, 0.f);
            float y3 = fmaxf(a.w*sc + of, 0.f);
            if (w0 < W3O){
                float mx = y0;
                if (w0+1 < W3O) mx = fmaxf(mx, y1);
                if (w0+2 < W3O) mx = fmaxf(mx, y2);
                if (w0+3 < W3O) mx = fmaxf(mx, y3);
                atomicMax((int*)&g_xcm[b*32 + oo], __float_as_int(mx));
            }
        }
    }
}

// ---------------- fused FC tail: 2 graphs/block, shared weight loads -------
// xd recomputed inline per graph (bit-identical pool/GEMV order); poolxd gone.

__global__ __launch_bounds__(1024) void k_tail(
    const void* fcxcW, const void* fcxcb,
    const void* bg, const void* bb, const void* bm, const void* bv,
    const void* fc1W, const void* fc1b,
    const void* fc2W, const void* fc2b,
    const void* outW, const void* outb, void* out,
    const void* fcxdW, const void* fcxdb)
{
    const int F = g_isf32;
    __shared__ float red0[8][32], red1[8][32];
    __shared__ float sz0[256], sz1[256];
    __shared__ float z1s0[1024], z1s1[1024];
    __shared__ float sp0[4][256], sp1[4][256];
    int b0 = blockIdx.x*2, b1 = b0 + 1, t = threadIdx.x;

    // ---- inline xd: pool (stride-8, exact poolxd order) for both graphs ----
    if (t < 512){
        int j = t & 31, sub = (t >> 5) & 7;
        int bg_ = (t < 256) ? b0 : b1;
        int s = g_gstart[bg_], e = g_gstart[bg_ + 1];
        float a = 0.f;
        for (int n = s + sub; n < e; n += 8) a += g_hB[n*32 + j];
        if (t < 256) red0[sub][j] = a; else red1[sub][j] = a;
    }
    __syncthreads();
    if (t < 32){
        int j = t;
        red0[0][j] = red0[0][j] + red0[1][j] + red0[2][j] + red0[3][j]
                   + red0[4][j] + red0[5][j] + red0[6][j] + red0[7][j];
    } else if (t < 64){
        int j = t - 32;
        red1[0][j] = red1[0][j] + red1[1][j] + red1[2][j] + red1[3][j]
                   + red1[4][j] + red1[5][j] + red1[6][j] + red1[7][j];
    }
    __syncthreads();
    if (t < 128){
        float acc = LD(fcxdb, t, F);
        #pragma unroll
        for (int i = 0; i < 32; i++) acc += red0[0][i] * LD(fcxdW, i*128 + t, F);
        sz0[t] = fmaxf(acc, 0.f);
    } else if (t < 256){
        int j = t - 128;
        float acc = LD(fcxdb, j, F);
        #pragma unroll
        for (int i = 0; i < 32; i++) acc += red1[0][i] * LD(fcxdW, i*128 + j, F);
        sz1[j] = fmaxf(acc, 0.f);
    } else if (t < 384){
        int j = t - 256;
        float a0 = LD(fcxcb, j, F), a1 = a0;
        #pragma unroll
        for (int i = 0; i < 32; i++){
            float w = LD(fcxcW, i*128 + j, F);
            a0 += g_xcm[b0*32 + i] * w;
            a1 += g_xcm[b1*32 + i] * w;
        }
        float inv = LD(bg, j, F) * rsqrtf(LD(bv, j, F) + BN_EPS);
        float bm_ = LD(bm, j, F), bb_ = LD(bb, j, F);
        sz0[128 + j] = fmaxf((a0 - bm_) * inv + bb_, 0.f);
        sz1[128 + j] = fmaxf((a1 - bm_) * inv + bb_, 0.f);
    }
    __syncthreads();
    {
        float a0 = LD(fc1b, t, F), a1 = a0;
        for (int i = 0; i < 256; i++){
            float w = LD(fc1W, i*1024 + t, F);
            a0 += sz0[i] * w;
            a1 += sz1[i] * w;
        }
        z1s0[t] = fmaxf(a0, 0.f);
        z1s1[t] = fmaxf(a1, 0.f);
    }
    __syncthreads();
    int j = t & 255, kq = t >> 8;
    {
        float a20 = 0.f, a21 = 0.f;
        #pragma unroll 8
        for (int i = 0; i < 256; i++){
            float w = LD(fc2W, (kq*256 + i)*256 + j, F);
            a20 += z1s0[kq*256 + i] * w;
            a21 += z1s1[kq*256 + i] * w;
        }
        sp0[kq][j] = a20;
        sp1[kq][j] = a21;
    }
    __syncthreads();
    if (t < 256){
        float bias = LD(fc2b, t, F), ow = LD(outW, t, F);
        float z20 = fmaxf(sp0[0][t] + sp0[1][t] + sp0[2][t] + sp0[3][t] + bias, 0.f);
        float z21 = fmaxf(sp1[0][t] + sp1[1][t] + sp1[2][t] + sp1[3][t] + bias, 0.f);
        sp0[0][t] = z20 * ow;
        sp1[0][t] = z21 * ow;
    }
    __syncthreads();
    for (int s = 128; s > 0; s >>= 1){
        if (t < s){
            sp0[0][t] += sp0[0][t + s];
            sp1[0][t] += sp1[0][t + s];
        }
        __syncthreads();
    }
    if (t == 0){
        float ob = LD(outb, 0, F);
        float r0 = sp0[0][0] + ob;
        float r1 = sp1[0][0] + ob;
        if (F){ ((float*)out)[b0] = r0; ((float*)out)[b1] = r1; }
        else  { ((bf16*)out)[b0] = __float2bfloat16(r0);
                ((bf16*)out)[b1] = __float2bfloat16(r1); }
    }
}

// ---------------- launch ----------------

extern "C" void kernel_launch(void* const* d_in, const int* in_sizes, int n_in,
                              void* d_out, int out_size, void* d_ws, size_t ws_size,
                              hipStream_t stream)
{
    (void)in_sizes; (void)n_in; (void)out_size; (void)d_ws; (void)ws_size;
    const void* x      = d_in[0];
    const int*  ei     = (const int*)d_in[1];
    const int*  batch  = (const int*)d_in[2];
    const int*  target = (const int*)d_in[3];
    const void* g1W1 = d_in[4];  const void* g1b1 = d_in[5];
    const void* g1W2 = d_in[6];  const void* g1b2 = d_in[7];
    const void* gW1  = d_in[8];  const void* gb1  = d_in[9];
    const void* gW2  = d_in[10]; const void* gb2  = d_in[11];
    const void* bng  = d_in[12]; const void* bnb  = d_in[13];
    const void* bnm  = d_in[14]; const void* bnv  = d_in[15];
    const void* fcxdW = d_in[16]; const void* fcxdb = d_in[17];
    const void* embed = d_in[18];
    const void* c1W = d_in[19]; const void* c1b = d_in[20];
    const void* c2W = d_in[21]; const void* c2b = d_in[22];
    const void* c3W = d_in[23]; const void* c3b = d_in[24];
    const void* cbng = d_in[25]; const void* cbnb = d_in[26];
    const void* cbnm = d_in[27]; const void* cbnv = d_in[28];
    const void* fcxcW = d_in[29]; const void* fcxcb = d_in[30];
    const void* bnfcg = d_in[31]; const void* bnfcb = d_in[32];
    const void* bnfcm = d_in[33]; const void* bnfcv = d_in[34];
    const void* fc1W = d_in[35]; const void* fc1b = d_in[36];
    const void* fc2W = d_in[37]; const void* fc2b = d_in[38];
    const void* outW = d_in[39]; const void* outb = d_in[40];

    // ---- prep: dtype+ranges+count+proj78 (GIN prerequisites only) ----
    k_prep<<<PREP_BLOCKS, 256, 0, stream>>>(x, ei, batch, g1W1);
    // ---- CSR finish ----
    k_scan<<<1, 1024, 0, stream>>>();
    k_fill<<<N_EDGES/256, 256, 0, stream>>>(ei);
    // ---- GIN chain; gin1b also carries wpack/P/wsum/xcm0 in 356 extra blocks ----
    k_gin1b<<<GIN1B_GIN + GIN1B_EXTRA, 256, 0, stream>>>(
        g1b1, g1W2, g1b2, bng, bnb, bnm, bnv, embed, c1W, c2W, c3W);
    for (int l = 0; l < 4; l++){
        k_gin32L<<<N_NODES/8, 256, 0, stream>>>(gW1, gb1, gW2, gb2,
                                                bng, bnb, bnm, bnv, l);
    }
    // ---- FUSED conv chain (r4-frozen phases + inline xdb; poolxd removed) ----
    k_cfuse<<<NB*8, 512, 0, stream>>>(target, cbng, cbnb, cbnm, cbnv, c2b, c3b,
                                      fcxdW, fcxdb, c1b);
    // ---- fused FC tail: 2 graphs/block, inline xd ----
    k_tail<<<NB/2, 1024, 0, stream>>>(fcxcW, fcxcb, bnfcg, bnfcb, bnfcm, bnfcv,
                                      fc1W, fc1b, fc2W, fc2b, outW, outb, d_out,
                                      fcxdW, fcxdb);
}

// Round 8
// 404.935 us; speedup vs baseline: 1.0546x; 1.0235x over previous
//
#include <hip/hip_runtime.h>
#include <hip/hip_bf16.h>

typedef __hip_bfloat16 bf16;
__device__ __forceinline__ float b2f(bf16 v){ return __bfloat162float(v); }

typedef __attribute__((ext_vector_type(8))) short s8v;
typedef __attribute__((ext_vector_type(4))) float f4v;

#define N_NODES 16384
#define N_EDGES 65536
#define NB 256
#define LSEQ 1000
#define BN_EPS 1e-5f
#define W1O 985
#define W2O 970
#define W3O 955

// ---- dtype flag: 1 if float inputs are f32, 0 if bf16 (measured: f32 on this harness) ----
__device__ int g_isf32;

__device__ __forceinline__ float LD(const void* p, int i, int f){
    return f ? ((const float*)p)[i] : b2f(((const bf16*)p)[i]);
}

// f32 -> bf16 bits, round-to-nearest-even
__device__ __forceinline__ unsigned short f2b(float x){
    unsigned u = __float_as_uint(x);
    return (unsigned short)((u + 0x7FFFu + ((u >> 16) & 1u)) >> 16);
}
__device__ __forceinline__ float bb2f(unsigned short h){
    return __uint_as_float(((unsigned)h) << 16);
}

// ---- intermediates in device globals ----
__device__ float g_hA[N_NODES*32];
__device__ float g_hB[N_NODES*32];
__device__ float g_xd[NB*128];
__device__ float g_P[16*26*32];
__device__ float g_wsum[32*128];
__device__ float g_xdb[NB*32];
__device__ float g_xcm[NB*32];
// pre-packed conv weights in per-lane B-FRAGMENT order (s8v granularity):
// s8v index = ktg*256 + ogrp*128 + hl*64 + lane
__device__ __attribute__((aligned(16))) unsigned short g_wf[2][32768];
// CSR of the (fixed) edge list, destination-major
// INVARIANT: g_deg is zero at k_prep entry (zero-init at load; k_scan re-zeroes
// it after consuming it each iteration) -> k_count can run inside k_prep.
__device__ int g_deg[N_NODES];
__device__ int g_cur[N_NODES];
__device__ int g_rowptr[N_NODES + 1];
__device__ int g_csrc[N_EDGES];
__device__ int g_gstart[NB + 1];     // per-graph node ranges (batch is sorted)

// ================= WIDE PREP KERNEL (no internal dependencies) ============
// Merges: dtype, wpack, Pw(P+wsum), xcm-zero, ranges, count, proj78
// (8 legacy dispatches -> 1). All tasks mutually independent; per-task math
// identical to the legacy kernels. Block ranges:
//   [0,256)    wpack        (65536 items)
//   [256,308)  P table      (13312 items)
//   [308,324)  wsum         (4096 items)
//   [324,325)  ranges       (256 items)
//   [325,357)  xcm zero     (8192 items)
//   [357,613)  edge count   (65536 edges, atomicAdd into pre-zeroed g_deg)
//   [613,2661) proj78       (8 nodes/block)
#define PREP_BLOCKS 2661

__global__ __launch_bounds__(256) void k_prep(
    const void* x, const int* __restrict__ ei, const int* __restrict__ batch,
    const void* g1W1, const void* embed, const void* c1W,
    const void* c2W, const void* c3W)
{
    __shared__ float sW1[78*32];
    __shared__ float sx[8][78];
    __shared__ int s_cnt;
    int tid = threadIdx.x, bid = blockIdx.x;

    // per-block dtype detect (same statistic as legacy k_dtype)
    if (tid == 0) s_cnt = 0;
    __syncthreads();
    {
        const unsigned short* u = (const unsigned short*)x;
        int bad = 0;
        for (int i = tid; i < 512; i += 256){
            unsigned short h = u[i];
            int ex = (h >> 7) & 0xFF;
            if (!(h == 0 || (ex >= 96 && ex <= 142))) bad++;
        }
        if (bad) atomicAdd(&s_cnt, bad);
    }
    __syncthreads();
    const int F = (s_cnt > 50) ? 1 : 0;
    if (bid == 0 && tid == 0) g_isf32 = F;      // consumed by k_cfuse / k_tail

    if (bid < 256){
        // ---- wpack (identical to legacy k_wpack) ----
        int idx = bid*256 + tid;
        int sel = idx >> 15;
        int r = idx & 32767;
        int j = r & 7;
        int lane = (r >> 3) & 63;
        int hl = (r >> 9) & 1;
        int ogrp = (r >> 10) & 1;
        int ktg = r >> 11;
        int c = (lane >> 4)*8 + j;
        int o = ogrp*16 + (lane & 15);
        const void* Wt = sel ? c3W : c2W;
        float wv = LD(Wt, o*512 + c*16 + ktg, F);
        unsigned short h = f2b(wv);
        g_wf[sel][r] = hl ? f2b(wv - bb2f(h)) : h;
    } else if (bid < 308){
        // ---- P table (identical to legacy k_Pw first branch) ----
        int idx = (bid - 256)*256 + tid;
        if (idx < 16*26*32){
            int o = idx & 31;
            int t = (idx >> 5) % 26;
            int k = idx / (32*26);
            float a = 0.f;
            for (int c = 0; c < 128; c++)
                a += LD(embed, t*128 + c, F) * LD(c1W, o*4096 + c*16 + k, F);
            g_P[(k*26 + t)*32 + o] = a;
        }
    } else if (bid < 324){
        // ---- wsum (identical to legacy k_Pw second branch) ----
        int idx = (bid - 308)*256 + tid;
        int o = idx >> 7, c = idx & 127;
        float a = 0.f;
        #pragma unroll
        for (int k = 0; k < 16; k++) a += LD(c1W, o*4096 + (128 + c)*16 + k, F);
        g_wsum[o*128 + c] = a;
    } else if (bid < 325){
        // ---- ranges (identical to legacy k_ranges) ----
        int b = tid;
        int lo = 0, hi = N_NODES;
        while (lo < hi){ int mid = (lo + hi) >> 1; if (batch[mid] < b) lo = mid + 1; else hi = mid; }
        g_gstart[b] = lo;
        if (b == 0) g_gstart[NB] = N_NODES;
    } else if (bid < 357){
        // ---- xcm zero ----
        int i = (bid - 325)*256 + tid;
        if (i < NB*32) g_xcm[i] = 0.f;
    } else if (bid < 613){
        // ---- edge count (g_deg pre-zeroed invariant) ----
        int e = (bid - 357)*256 + tid;
        atomicAdd(&g_deg[ei[N_EDGES + e]], 1);
    } else {
        // ---- proj78 (identical math to legacy k_proj78) ----
        for (int i = tid; i < 78*32; i += 256) sW1[i] = LD(g1W1, i, F);
        int nodeBase = (bid - 613)*8;
        for (int i = tid; i < 8*78; i += 256){
            int ln = i / 78, f = i - ln*78;
            sx[ln][f] = LD(x, (nodeBase + ln)*78 + f, F);
        }
        __syncthreads();
        int ln = tid >> 5, j = tid & 31;
        float a = 0.f;
        #pragma unroll 6
        for (int i = 0; i < 78; i++) a += sx[ln][i] * sW1[i*32 + j];
        g_hA[(nodeBase + ln)*32 + j] = a;
    }
}

// ---- CSR scan: consumes g_deg, re-zeroes it for the next iteration ----
__global__ __launch_bounds__(1024) void k_scan(){                            // 1 block
    __shared__ int part[1024];
    int t = threadIdx.x;
    int base = t*16;
    int s = 0;
    #pragma unroll
    for (int i = 0; i < 16; i++) s += g_deg[base + i];
    part[t] = s;
    __syncthreads();
    for (int off = 1; off < 1024; off <<= 1){
        int v = (t >= off) ? part[t - off] : 0;
        __syncthreads();
        part[t] += v;
        __syncthreads();
    }
    int run = (t == 0) ? 0 : part[t - 1];
    for (int i = 0; i < 16; i++){
        g_rowptr[base + i] = run;
        g_cur[base + i] = run;
        run += g_deg[base + i];
        g_deg[base + i] = 0;         // restore the zero invariant for k_prep
    }
    if (t == 1023) g_rowptr[N_NODES] = run;
}
__global__ void k_fill(const int* __restrict__ ei){
    int e = blockIdx.x*256 + threadIdx.x;                                    // grid 256
    int d = ei[N_EDGES + e];
    int slot = atomicAdd(&g_cur[d], 1);
    g_csrc[slot] = ei[e];
}

// cooperative edge gather: 32 lanes of a node load up to 32 indices at once,
// broadcast via shuffle -> feature gathers become independent (same sum order)
__device__ __forceinline__ float csr_gather(const float* hin, int n, int j){
    int rs = g_rowptr[n];
    int deg = g_rowptr[n + 1] - rs;
    float agg = 0.f;
    for (int base = 0; base < deg; base += 32){
        int cnt = deg - base; if (cnt > 32) cnt = 32;
        int myidx = (j < cnt) ? g_csrc[rs + base + j] : 0;
        for (int e = 0; e < cnt; e++){
            int src = __shfl(myidx, e, 32);
            agg += hin[src*32 + j];
        }
    }
    return agg;
}

// hA -> hB
__global__ __launch_bounds__(256) void k_gin1b(
    const void* b1, const void* W2, const void* b2,
    const void* bng, const void* bnb, const void* bnm, const void* bnv)
{
    const int F = g_isf32;
    __shared__ float sW2[32*32];
    __shared__ float sb1[32], sb2[32], sA[32], sB[32];
    __shared__ float st[8][32];
    int tid = threadIdx.x;
    for (int i = tid; i < 1024; i += 256) sW2[i] = LD(W2, i, F);
    if (tid < 32){
        sb1[tid] = LD(b1, tid, F); sb2[tid] = LD(b2, tid, F);
        float inv = LD(bng, tid, F) * rsqrtf(LD(bnv, tid, F) + BN_EPS);
        sA[tid] = inv;
        sB[tid] = LD(bnb, tid, F) - LD(bnm, tid, F) * inv;
    }
    __syncthreads();
    int ln = tid >> 5, j = tid & 31;
    int n = blockIdx.x*8 + ln;
    float agg = csr_gather(g_hA, n, j);
    st[ln][j] = fmaxf(g_hA[n*32 + j] + agg + sb1[j], 0.f);
    __syncthreads();
    float t2 = sb2[j];
    #pragma unroll
    for (int i = 0; i < 32; i++) t2 += st[ln][i] * sW2[i*32 + j];
    t2 = fmaxf(t2, 0.f);
    g_hB[n*32 + j] = t2 * sA[j] + sB[j];
}

// alternating hB->hA (l even) / hA->hB (l odd)
__global__ __launch_bounds__(256) void k_gin32L(
    const void* W1, const void* b1, const void* W2, const void* b2,
    const void* bng, const void* bnb, const void* bnm, const void* bnv, int l)
{
    const int F = g_isf32;
    const float* hin = (l & 1) ? g_hA : g_hB;
    float* hout = (l & 1) ? g_hB : g_hA;
    const int oW = l*1024, ob = l*32, obn = (l+1)*32;
    __shared__ float sW1[32*32], sW2[32*32];
    __shared__ float sb1[32], sb2[32], sA[32], sB[32];
    __shared__ float sh[8][32], st[8][32];
    int tid = threadIdx.x;
    for (int i = tid; i < 1024; i += 256){ sW1[i] = LD(W1, oW + i, F); sW2[i] = LD(W2, oW + i, F); }
    if (tid < 32){
        sb1[tid] = LD(b1, ob + tid, F); sb2[tid] = LD(b2, ob + tid, F);
        float inv = LD(bng, obn + tid, F) * rsqrtf(LD(bnv, obn + tid, F) + BN_EPS);
        sA[tid] = inv;
        sB[tid] = LD(bnb, obn + tid, F) - LD(bnm, obn + tid, F) * inv;
    }
    int ln = tid >> 5, j = tid & 31;
    int n = blockIdx.x*8 + ln;
    float agg = csr_gather(hin, n, j);
    sh[ln][j] = hin[n*32 + j] + agg;
    __syncthreads();
    float t1 = sb1[j];
    #pragma unroll
    for (int i = 0; i < 32; i++) t1 += sh[ln][i] * sW1[i*32 + j];
    st[ln][j] = fmaxf(t1, 0.f);
    __syncthreads();
    float t2 = sb2[j];
    #pragma unroll
    for (int i = 0; i < 32; i++) t2 += st[ln][i] * sW2[i*32 + j];
    t2 = fmaxf(t2, 0.f);
    hout[n*32 + j] = t2 * sA[j] + sB[j];
}

// fused pool (range-based) + xd + xdbias; final h lives in g_hB
__global__ __launch_bounds__(256) void k_poolxd(const void* W, const void* bias,
                                                const void* c1b){
    const int F = g_isf32;
    __shared__ float red[8][32];
    __shared__ float sxd[128];
    int b = blockIdx.x, tid = threadIdx.x;
    int j = tid & 31, sub = tid >> 5;
    int s = g_gstart[b], e = g_gstart[b + 1];
    float a = 0.f;
    for (int n = s + sub; n < e; n += 8) a += g_hB[n*32 + j];
    red[sub][j] = a;
    __syncthreads();
    if (sub == 0){
        red[0][j] = red[0][j] + red[1][j] + red[2][j] + red[3][j]
                  + red[4][j] + red[5][j] + red[6][j] + red[7][j];
    }
    __syncthreads();
    if (tid < 128){
        float acc = LD(bias, tid, F);
        #pragma unroll
        for (int i = 0; i < 32; i++) acc += red[0][i] * LD(W, i*128 + tid, F);
        float xdv = fmaxf(acc, 0.f);
        g_xd[b*128 + tid] = xdv;
        sxd[tid] = xdv;
    }
    __syncthreads();
    if (tid < 32){
        float a2 = LD(c1b, tid, F);
        for (int c = 0; c < 128; c++) a2 += sxd[c] * g_wsum[tid*128 + c];
        g_xdb[b*32 + tid] = a2;
    }
}

// ---------------- FUSED conv1+conv2+conv3 (best-measured r4 version) ------
//  - __launch_bounds__(512,6): 6 waves/EU = the LDS-limited 24 waves/CU.
//  - Phase A: two rows in flight (independent accumulators, same per-row
//    k-ascending order; W1O guard moved to the final select).
//  - Phases B/C: ktg unrolled by 2 with a 2-pair named-register weight
//    prefetch.

#define FT_W 128
#define C1R 160      // need rows 0..158
#define C2R 144      // need rows 0..142 read, 0..143 written
#define CPAD 40      // 80 B rows: 16B-aligned, uniform 8-lane/bank-group (b128 floor)
#define STGN 176

__global__ __launch_bounds__(512, 6) void k_cfuse(
    const int* __restrict__ target,
    const void* g, const void* be, const void* m, const void* v,   // cbn* stacked [3][32]
    const void* c2b, const void* c3b)
{
    const int F = g_isf32;
    __shared__ int stg[STGN];
    __shared__ __attribute__((aligned(16))) unsigned short sC1h[C1R*CPAD]; // 12800 B
    __shared__ __attribute__((aligned(16))) unsigned short sC1l[C1R*CPAD]; // 12800 B
    __shared__ __attribute__((aligned(16))) unsigned short sC2h[C2R*CPAD]; // 11520 B
    __shared__ __attribute__((aligned(16))) unsigned short sC2l[C2R*CPAD]; // 11520 B
    __shared__ float sxb[32], sA1[32], sB1[32], sSc2[32], sOf2[32], sSc3[32], sOf3[32];
    int b = blockIdx.x >> 3;
    int tile = blockIdx.x & 7;
    int wbase = tile * FT_W;
    int tid = threadIdx.x;

    for (int i = tid; i < STGN; i += 512){
        int gi = wbase + i;
        stg[i] = (gi < LSEQ) ? target[b*LSEQ + gi] : 0;
    }
    if (tid < 32){
        sxb[tid] = g_xdb[b*32 + tid];
        float i1 = LD(g, tid, F) * rsqrtf(LD(v, tid, F) + BN_EPS);
        sA1[tid] = i1;
        sB1[tid] = LD(be, tid, F) - LD(m, tid, F) * i1;
        float i2 = LD(g, 32 + tid, F) * rsqrtf(LD(v, 32 + tid, F) + BN_EPS);
        sSc2[tid] = i2;
        sOf2[tid] = LD(be, 32 + tid, F) + (LD(c2b, tid, F) - LD(m, 32 + tid, F)) * i2;
        float i3 = LD(g, 64 + tid, F) * rsqrtf(LD(v, 64 + tid, F) + BN_EPS);
        sSc3[tid] = i3;
        sOf3[tid] = LD(be, 64 + tid, F) + (LD(c3b, tid, F) - LD(m, 64 + tid, F)) * i3;
    }
    __syncthreads();

    // ---- Phase A: conv1, TWO rows in flight (5 iterations x 2 rows) ----
    {
        int o = tid & 31, rsub = tid >> 5;          // rsub 0..15
        float iA = sA1[o], iB = sB1[o], xb = sxb[o];
        for (int r0 = rsub; r0 < C1R; r0 += 32){
            int r1 = r0 + 16;                       // < 160 always
            float a0 = xb, a1 = xb;
            #pragma unroll
            for (int k = 0; k < 16; k++){
                a0 += g_P[(k*26 + stg[r0 + k])*32 + o];
                a1 += g_P[(k*26 + stg[r1 + k])*32 + o];
            }
            float v0 = (wbase + r0 < W1O) ? fmaxf(a0 * iA + iB, 0.f) : 0.f;
            float v1 = (wbase + r1 < W1O) ? fmaxf(a1 * iA + iB, 0.f) : 0.f;
            unsigned short h0 = f2b(v0), h1 = f2b(v1);
            sC1h[r0*CPAD + o] = h0;
            sC1l[r0*CPAD + o] = f2b(v0 - bb2f(h0));
            sC1h[r1*CPAD + o] = h1;
            sC1l[r1*CPAD + o] = f2b(v1 - bb2f(h1));
        }
    }
    __syncthreads();

    int lane = tid & 63;
    int wv = tid >> 6;                  // 0..7
    int ml = lane & 15, quad = lane >> 4;
    int ogrp = wv & 1;
    int part = wv >> 1;                 // 0..3
    int oo = ogrp*16 + ml;

    // ---- Phase B: conv2 rows [0,144); m-tiles mt = part + 4*i ----
    {
        const s8v* wfb = (const s8v*)&g_wf[0][0] + ogrp*128 + lane;
        int nmt = (part == 0) ? 3 : 2;   // part0: mt 0,4,8 ; part p: mt p, p+4
        f4v acc[3];
        #pragma unroll
        for (int i = 0; i < 3; i++) acc[i] = (f4v){0.f,0.f,0.f,0.f};
        s8v bhA = wfb[0],   blA = wfb[64];
        s8v bhB = wfb[256], blB = wfb[320];
        for (int ktg = 0; ktg < 16; ktg += 2){
            s8v ch = bhA, cl = blA;
            if (ktg + 2 < 16){ bhA = wfb[(ktg+2)*256]; blA = wfb[(ktg+2)*256 + 64]; }
            #pragma unroll
            for (int i = 0; i < 3; i++){
                if (i < nmt){
                    int row = (part + 4*i)*16 + ml + ktg;       // <= 158
                    int aidx = row*CPAD + quad*8;
                    s8v ah = *(const s8v*)&sC1h[aidx];
                    s8v al = *(const s8v*)&sC1l[aidx];
                    acc[i] = __builtin_amdgcn_mfma_f32_16x16x32_bf16(ah, ch, acc[i], 0, 0, 0);
                    acc[i] = __builtin_amdgcn_mfma_f32_16x16x32_bf16(ah, cl, acc[i], 0, 0, 0);
                    acc[i] = __builtin_amdgcn_mfma_f32_16x16x32_bf16(al, ch, acc[i], 0, 0, 0);
                }
            }
            s8v dh = bhB, dl = blB;
            if (ktg + 3 < 16){ bhB = wfb[(ktg+3)*256]; blB = wfb[(ktg+3)*256 + 64]; }
            #pragma unroll
            for (int i = 0; i < 3; i++){
                if (i < nmt){
                    int row = (part + 4*i)*16 + ml + ktg + 1;   // <= 158
                    int aidx = row*CPAD + quad*8;
                    s8v ah = *(const s8v*)&sC1h[aidx];
                    s8v al = *(const s8v*)&sC1l[aidx];
                    acc[i] = __builtin_amdgcn_mfma_f32_16x16x32_bf16(ah, dh, acc[i], 0, 0, 0);
                    acc[i] = __builtin_amdgcn_mfma_f32_16x16x32_bf16(ah, dl, acc[i], 0, 0, 0);
                    acc[i] = __builtin_amdgcn_mfma_f32_16x16x32_bf16(al, dh, acc[i], 0, 0, 0);
                }
            }
        }
        float sc = sSc2[oo], of = sOf2[oo];
        #pragma unroll
        for (int i = 0; i < 3; i++){
            if (i < nmt){
                int mt = part + 4*i;
                f4v a = acc[i];
                float ys[4] = {a.x, a.y, a.z, a.w};
                #pragma unroll
                for (int rr = 0; rr < 4; rr++){
                    int row = mt*16 + quad*4 + rr;              // <= 143
                    float y = fmaxf(ys[rr]*sc + of, 0.f);
                    unsigned short h = f2b(y);
                    sC2h[row*CPAD + oo] = h;
                    sC2l[row*CPAD + oo] = f2b(y - bb2f(h));
                }
            }
        }
    }
    __syncthreads();

    // ---- Phase C: conv3 + maxpool epilogue ----
    {
        const s8v* wfb = (const s8v*)&g_wf[1][0] + ogrp*128 + lane;
        f4v acc[2];
        #pragma unroll
        for (int i = 0; i < 2; i++) acc[i] = (f4v){0.f,0.f,0.f,0.f};
        s8v bhA = wfb[0],   blA = wfb[64];
        s8v bhB = wfb[256], blB = wfb[320];
        for (int ktg = 0; ktg < 16; ktg += 2){
            s8v ch = bhA, cl = blA;
            if (ktg + 2 < 16){ bhA = wfb[(ktg+2)*256]; blA = wfb[(ktg+2)*256 + 64]; }
            #pragma unroll
            for (int i = 0; i < 2; i++){
                int row = (part + 4*i)*16 + ml + ktg;           // <= 142
                int aidx = row*CPAD + quad*8;
                s8v ah = *(const s8v*)&sC2h[aidx];
                s8v al = *(const s8v*)&sC2l[aidx];
                acc[i] = __builtin_amdgcn_mfma_f32_16x16x32_bf16(ah, ch, acc[i], 0, 0, 0);
                acc[i] = __builtin_amdgcn_mfma_f32_16x16x32_bf16(ah, cl, acc[i], 0, 0, 0);
                acc[i] = __builtin_amdgcn_mfma_f32_16x16x32_bf16(al, ch, acc[i], 0, 0, 0);
            }
            s8v dh = bhB, dl = blB;
            if (ktg + 3 < 16){ bhB = wfb[(ktg+3)*256]; blB = wfb[(ktg+3)*256 + 64]; }
            #pragma unroll
            for (int i = 0; i < 2; i++){
                int row = (part + 4*i)*16 + ml + ktg + 1;       // <= 142
                int aidx = row*CPAD + quad*8;
                s8v ah = *(const s8v*)&sC2h[aidx];
                s8v al = *(const s8v*)&sC2l[aidx];
                acc[i] = __builtin_amdgcn_mfma_f32_16x16x32_bf16(ah, dh, acc[i], 0, 0, 0);
                acc[i] = __builtin_amdgcn_mfma_f32_16x16x32_bf16(ah, dl, acc[i], 0, 0, 0);
                acc[i] = __builtin_amdgcn_mfma_f32_16x16x32_bf16(al, dh, acc[i], 0, 0, 0);
            }
        }
        float sc = sSc3[oo], of = sOf3[oo];
        #pragma unroll
        for (int i = 0; i < 2; i++){
            int mt = part + 4*i;
            int w0 = wbase + mt*16 + quad*4;
            f4v a = acc[i];
            float y0 = fmaxf(a.x*sc + of, 0.f);
            float y1 = fmaxf(a.y*sc + of, 0.f);
            float y2 = fmaxf(a.z*sc + of, 0.f);
            float y3 = fmaxf(a.w*sc + of, 0.f);
            if (w0 < W3O){
                float mx = y0;
                if (w0+1 < W3O) mx = fmaxf(mx, y1);
                if (w0+2 < W3O) mx = fmaxf(mx, y2);
                if (w0+3 < W3O) mx = fmaxf(mx, y3);
                atomicMax((int*)&g_xcm[b*32 + oo], __float_as_int(mx));
            }
        }
    }
}

// ---------------- fused FC tail: xcf -> fc1 -> fc2 -> out (per-b) -----------

__global__ __launch_bounds__(1024) void k_tail(
    const void* fcxcW, const void* fcxcb,
    const void* bg, const void* bb, const void* bm, const void* bv,
    const void* fc1W, const void* fc1b,
    const void* fc2W, const void* fc2b,
    const void* outW, const void* outb, void* out)
{
    const int F = g_isf32;
    __shared__ float sz[256];
    __shared__ float z1s[1024];
    __shared__ float sp[4][256];
    int b = blockIdx.x, t = threadIdx.x;
    if (t < 128) sz[t] = g_xd[b*128 + t];
    else if (t < 256){
        int j = t - 128;
        float a = LD(fcxcb, j, F);
        #pragma unroll
        for (int i = 0; i < 32; i++) a += g_xcm[b*32 + i] * LD(fcxcW, i*128 + j, F);
        float inv = LD(bg, j, F) * rsqrtf(LD(bv, j, F) + BN_EPS);
        a = (a - LD(bm, j, F)) * inv + LD(bb, j, F);
        sz[t] = fmaxf(a, 0.f);
    }
    __syncthreads();
    float a = LD(fc1b, t, F);
    for (int i = 0; i < 256; i++) a += sz[i] * LD(fc1W, i*1024 + t, F);
    z1s[t] = fmaxf(a, 0.f);
    __syncthreads();
    int j = t & 255, kq = t >> 8;
    float a2 = 0.f;
    #pragma unroll 8
    for (int i = 0; i < 256; i++)
        a2 += z1s[kq*256 + i] * LD(fc2W, (kq*256 + i)*256 + j, F);
    sp[kq][j] = a2;
    __syncthreads();
    if (t < 256){
        float z2 = fmaxf(sp[0][t] + sp[1][t] + sp[2][t] + sp[3][t] + LD(fc2b, t, F), 0.f);
        sp[0][t] = z2 * LD(outW, t, F);
    }
    __syncthreads();
    for (int s = 128; s > 0; s >>= 1){
        if (t < s) sp[0][t] += sp[0][t + s];
        __syncthreads();
    }
    if (t == 0){
        float r = sp[0][0] + LD(outb, 0, F);
        if (F) ((float*)out)[b] = r;
        else   ((bf16*)out)[b] = __float2bfloat16(r);
    }
}

// ---------------- launch ----------------

extern "C" void kernel_launch(void* const* d_in, const int* in_sizes, int n_in,
                              void* d_out, int out_size, void* d_ws, size_t ws_size,
                              hipStream_t stream)
{
    (void)in_sizes; (void)n_in; (void)out_size; (void)d_ws; (void)ws_size;
    const void* x      = d_in[0];
    const int*  ei     = (const int*)d_in[1];
    const int*  batch  = (const int*)d_in[2];
    const int*  target = (const int*)d_in[3];
    const void* g1W1 = d_in[4];  const void* g1b1 = d_in[5];
    const void* g1W2 = d_in[6];  const void* g1b2 = d_in[7];
    const void* gW1  = d_in[8];  const void* gb1  = d_in[9];
    const void* gW2  = d_in[10]; const void* gb2  = d_in[11];
    const void* bng  = d_in[12]; const void* bnb  = d_in[13];
    const void* bnm  = d_in[14]; const void* bnv  = d_in[15];
    const void* fcxdW = d_in[16]; const void* fcxdb = d_in[17];
    const void* embed = d_in[18];
    const void* c1W = d_in[19]; const void* c1b = d_in[20];
    const void* c2W = d_in[21]; const void* c2b = d_in[22];
    const void* c3W = d_in[23]; const void* c3b = d_in[24];
    const void* cbng = d_in[25]; const void* cbnb = d_in[26];
    const void* cbnm = d_in[27]; const void* cbnv = d_in[28];
    const void* fcxcW = d_in[29]; const void* fcxcb = d_in[30];
    const void* bnfcg = d_in[31]; const void* bnfcb = d_in[32];
    const void* bnfcm = d_in[33]; const void* bnfcv = d_in[34];
    const void* fc1W = d_in[35]; const void* fc1b = d_in[36];
    const void* fc2W = d_in[37]; const void* fc2b = d_in[38];
    const void* outW = d_in[39]; const void* outb = d_in[40];

    // ---- wide prep: dtype+wpack+Pw+wsum+xcm0+ranges+count+proj78 (1 dispatch) ----
    k_prep<<<PREP_BLOCKS, 256, 0, stream>>>(x, ei, batch, g1W1, embed, c1W, c2W, c3W);
    // ---- CSR finish ----
    k_scan<<<1, 1024, 0, stream>>>();
    k_fill<<<N_EDGES/256, 256, 0, stream>>>(ei);
    // ---- GIN chain (8 nodes/block; h ping-pongs hA->hB->hA->...) ----
    k_gin1b<<<N_NODES/8, 256, 0, stream>>>(g1b1, g1W2, g1b2, bng, bnb, bnm, bnv);
    for (int l = 0; l < 4; l++){
        k_gin32L<<<N_NODES/8, 256, 0, stream>>>(gW1, gb1, gW2, gb2,
                                                bng, bnb, bnm, bnv, l);
    }
    // ---- pool+xd+xdbias fused ----
    k_poolxd<<<NB, 256, 0, stream>>>(fcxdW, fcxdb, c1b);
    // ---- FUSED conv chain (one dispatch, 8 waves/block, deep prefetch) ----
    k_cfuse<<<NB*8, 512, 0, stream>>>(target, cbng, cbnb, cbnm, cbnv, c2b, c3b);
    // ---- fused FC tail ----
    k_tail<<<NB, 1024, 0, stream>>>(fcxcW, fcxcb, bnfcg, bnfcb, bnfcm, bnfcv,
                                    fc1W, fc1b, fc2W, fc2b, outW, outb, d_out);
}